// Round 1
// baseline (488.527 us; speedup 1.0000x reference)
//
#include <hip/hip_runtime.h>
#include <hip/hip_bf16.h>

#define N_NODES 10000
#define N_EDGES 160000
#define HID 300
#define HIDP 304
#define NPARTB (N_EDGES - N_NODES)   // 150000
#define KS 328                        // H-plane k-stride in shorts
#define RBM 80                        // mega rows/block (5 M-tiles); exact 1875
#define RBF 16                        // fuse rows/block (1 M-tile) -> 625 blocks
#define PARTB_BLOCKS 1875             // 150000/80 exact
#define GEMMA_BLOCKS 125              // 10000/80 exact
#define FILL_BLOCKS 313               // ceil(160000/512)
#define MEGA_BLOCKS (PARTB_BLOCKS + GEMMA_BLOCKS + FILL_BLOCKS)
#define FUSE_BLOCKS 625               // 10000/16 exact

typedef __attribute__((ext_vector_type(8))) short short8;
typedef __attribute__((ext_vector_type(4))) short s16x4;
typedef __attribute__((ext_vector_type(4))) float f32x4;

#define MFMA_B16(a, b, c) __builtin_amdgcn_mfma_f32_16x16x32_bf16(a, b, c, 0, 0, 0)

__device__ __forceinline__ short bf16r(float x) {
    unsigned u = __float_as_uint(x);
    return (short)((u + 0x7fffu + ((u >> 16) & 1u)) >> 16);
}
__device__ __forceinline__ float b2f(unsigned short u) {
    return __uint_as_float(((unsigned)u) << 16);
}
__device__ __forceinline__ void split1(float x, short& hi, short& lo) {
    short h = bf16r(x);
    float hf = __uint_as_float(((unsigned)(unsigned short)h) << 16);
    hi = h;
    lo = bf16r(x - hf);
}

// ---------------------------------------------------------------------------
// k_prep: weight pre-split (layout verified R2-R11) + degree count.
// ---------------------------------------------------------------------------
__global__ void k_prep(const float* __restrict__ g0w, const float* __restrict__ gw,
                       short* __restrict__ wt0, short* __restrict__ wtl,
                       const int* __restrict__ col, int* __restrict__ cnt) {
    int idx = blockIdx.x * 256 + threadIdx.x;
    if (idx < N_EDGES) atomicAdd(&cnt[col[idx]], 1);
    if (idx < 1216) {
        int n16 = idx & 15, q = (idx >> 4) & 3, nt = idx >> 6;
        int n = nt * 16 + n16;
        short* hd = wt0 + (size_t)(nt * 8 + q) * 128 + n16 * 8;
        short* ld = wt0 + (size_t)(nt * 8 + 4 + q) * 128 + n16 * 8;
#pragma unroll
        for (int j = 0; j < 8; ++j) {
            int k = q * 8 + j;
            float f = (n < HID) ? g0w[k * HID + n] : 0.0f;
            short hi, lo;
            split1(f, hi, lo);
            hd[j] = hi;
            ld[j] = lo;
        }
    } else if (idx < 1216 + 48640) {
        int i = idx - 1216;
        int n16 = i & 15; i >>= 4;
        int q = i & 3; i >>= 2;
        int nt = i % 19; i /= 19;
        int chunk = i % 10;
        int l = i / 10;
        int n = nt * 16 + n16;
        int cnt_idx = chunk * 19 + nt;
        short* base = wtl + (size_t)l * 194560;
        short* hd = base + (size_t)(cnt_idx * 8 + q) * 128 + n16 * 8;
        short* ld = base + (size_t)(cnt_idx * 8 + 4 + q) * 128 + n16 * 8;
#pragma unroll
        for (int j = 0; j < 8; ++j) {
            int k = chunk * 32 + q * 8 + j;
            float f = (k < HID && n < HID) ? gw[((size_t)l * HID + k) * HID + n] : 0.0f;
            short hi, lo;
            split1(f, hi, lo);
            hd[j] = hi;
            ld[j] = lo;
        }
    }
}

// k_scan: 1024 threads, 10 iterations (R10/R11-verified)
__global__ __launch_bounds__(1024) void k_scan(
    const int* __restrict__ cnt, int* __restrict__ col_start,
    int* __restrict__ cursor, float* __restrict__ dinv,
    float* __restrict__ selfnorm) {
    __shared__ int wsum[16];
    int t = threadIdx.x;
    int lane = t & 63, w = t >> 6;
    int carry = 0;
    for (int base = 0; base < N_NODES; base += 1024) {
        int i = base + t;
        int v = (i < N_NODES) ? cnt[i] : 0;
        int s = v;
#pragma unroll
        for (int d = 1; d < 64; d <<= 1) {
            int n = __shfl_up(s, d, 64);
            if (lane >= d) s += n;
        }
        if (lane == 63) wsum[w] = s;
        __syncthreads();
        int woff = 0, total = 0;
#pragma unroll
        for (int k = 0; k < 16; ++k) {
            if (k < w) woff += wsum[k];
            total += wsum[k];
        }
        if (i < N_NODES) {
            int excl = carry + woff + s - v;
            col_start[i] = excl;
            cursor[i] = excl;
            float dd = (float)v + 1.0f;
            dinv[i] = rsqrtf(dd);
            selfnorm[i] = 1.0f / dd;
        }
        carry += total;
        __syncthreads();
    }
    if (t == 0) col_start[N_NODES] = carry;
}

// ---------------------------------------------------------------------------
// GCN core: MT 16-row tiles/wave, NTC n-tiles, 2-term split-bf16, runtime
// chunk loop (unroll 1 — spill lesson), single-buffered.
// SWAP=true computes C^T (operands exchanged): lane then holds
// (feature = quad*4+r, row = mt*16+l16) -> enables 8B vectorized, 2-way-only
// LDS epilogue writes (kills the 4-way b16-store bank conflicts).
// ---------------------------------------------------------------------------
template <int MT, int NTC, bool SWAP>
__device__ __forceinline__ void kloop(const short* __restrict__ wp, int nch,
                                      const short* Hh, int nt0, int quad, int l16,
                                      f32x4 (&acc)[MT][NTC]) {
#pragma unroll
    for (int mt = 0; mt < MT; ++mt)
#pragma unroll
        for (int i = 0; i < NTC; ++i)
#pragma unroll
            for (int r = 0; r < 4; ++r) acc[mt][i][r] = 0.0f;
#pragma unroll 1
    for (int c = 0; c < nch; ++c) {
        const short* cb = wp + (size_t)(c * 19 + nt0) * 1024 + quad * 128 + l16 * 8;
        short8 ah[MT];
#pragma unroll
        for (int mt = 0; mt < MT; ++mt)
            ah[mt] = *(const short8*)&Hh[(mt * 16 + l16) * KS + c * 32 + quad * 8];
        short8 bb[NTC];
#pragma unroll
        for (int i = 0; i < NTC; ++i) bb[i] = *(const short8*)(cb + (size_t)i * 1024);
#pragma unroll
        for (int mt = 0; mt < MT; ++mt)
#pragma unroll
            for (int i = 0; i < NTC; ++i)
                acc[mt][i] = SWAP ? MFMA_B16(bb[i], ah[mt], acc[mt][i])
                                  : MFMA_B16(ah[mt], bb[i], acc[mt][i]);
#pragma unroll
        for (int i = 0; i < NTC; ++i) bb[i] = *(const short8*)(cb + (size_t)i * 1024 + 512);
#pragma unroll
        for (int mt = 0; mt < MT; ++mt)
#pragma unroll
            for (int i = 0; i < NTC; ++i)
                acc[mt][i] = SWAP ? MFMA_B16(bb[i], ah[mt], acc[mt][i])
                                  : MFMA_B16(ah[mt], bb[i], acc[mt][i]);
    }
}

// Transposed epilogue: lane writes 4 consecutive features of one row as one
// aligned 8B ds_write_b64. Within a quarter-wave rows vary (stride 656B ==
// 4 banks) -> 2-way aliasing only (free).
template <int MT, int NTC>
__device__ __forceinline__ void gcn_epilogueT(const float* __restrict__ bias,
                                              int nt0, int quad, int l16,
                                              f32x4 (&acc)[MT][NTC], short* Hh) {
#pragma unroll
    for (int i = 0; i < NTC; ++i) {
        int f0 = (nt0 + i) * 16 + quad * 4;
        float bv[4];
#pragma unroll
        for (int r = 0; r < 4; ++r) bv[r] = (f0 + r < HID) ? bias[f0 + r] : 0.0f;
#pragma unroll
        for (int mt = 0; mt < MT; ++mt) {
            s16x4 pk;
#pragma unroll
            for (int r = 0; r < 4; ++r)
                pk[r] = bf16r(fmaxf(acc[mt][i][r] + bv[r], 0.0f));
            *(s16x4*)&Hh[(mt * 16 + l16) * KS + f0] = pk;
        }
    }
}

// final partB layer (transposed acc): per (i,r) feature, sum relu over all
// 80 rows = local mt-sum + xor-shuffle reduce over the 16 l16 lanes.
template <int MT, int NTC>
__device__ __forceinline__ void gcn_finalT(const float* __restrict__ bias,
                                           int nt0, int quad, int l16,
                                           f32x4 (&acc)[MT][NTC],
                                           float* __restrict__ gout) {
#pragma unroll
    for (int i = 0; i < NTC; ++i) {
        int f0 = (nt0 + i) * 16 + quad * 4;
#pragma unroll
        for (int r = 0; r < 4; ++r) {
            int f = f0 + r;
            float b = (f < HID) ? bias[f] : 0.0f;
            float s = 0.0f;
#pragma unroll
            for (int mt = 0; mt < MT; ++mt) s += fmaxf(acc[mt][i][r] + b, 0.0f);
            s += __shfl_xor(s, 1, 64);
            s += __shfl_xor(s, 2, 64);
            s += __shfl_xor(s, 4, 64);
            s += __shfl_xor(s, 8, 64);
            if (l16 == 0) gout[f] = (f < HID) ? s : 0.0f;
        }
    }
}

// non-transposed global output (coalesced 2B x 16-lane row segments)
template <int MT, int NTC>
__device__ __forceinline__ void gemm_out(int base, int nt0, int quad, int l16,
                                         f32x4 (&acc)[MT][NTC],
                                         unsigned short* __restrict__ HW) {
#pragma unroll
    for (int i = 0; i < NTC; ++i) {
        int c = (nt0 + i) * 16 + l16;
#pragma unroll
        for (int mt = 0; mt < MT; ++mt)
#pragma unroll
            for (int r = 0; r < 4; ++r) {
                int gm = base + mt * 16 + quad * 4 + r;
                if (gm < N_NODES)
                    HW[(size_t)gm * HIDP + c] = (unsigned short)bf16r(acc[mt][i][r]);
            }
    }
}

// ---------------------------------------------------------------------------
// k_mega: CSR-fill (313, first: short blocks out of the way, uniform heavy
// tail) U gemmA-L0 (125) U partB (1875, 80 rows, 5 M-tiles, fused 5-layer).
// (512,4): reg budget 128; LDS 52480 B -> 2 blocks/CU = 16 waves/CU.
// ---------------------------------------------------------------------------
__global__ __launch_bounds__(512, 4) void k_mega(
    const float* __restrict__ edge_attr,
    const float* __restrict__ edge_w,
    const float* __restrict__ edge_b,
    const short* __restrict__ wt0,
    const short* __restrict__ wtl,
    const float* __restrict__ gcn0_b,
    const float* __restrict__ gcn_b,
    float* __restrict__ gpartB,      // [PARTB_BLOCKS][HIDP] plain partials
    unsigned short* __restrict__ hw0,
    const int* __restrict__ row,
    const int* __restrict__ col,
    int* __restrict__ cursor,
    const float* __restrict__ dinv,
    int2* __restrict__ edge_pack) {
    __shared__ short Hh[RBM * KS];   // 52480 B
    int bid = blockIdx.x, t = threadIdx.x;
    int lane = t & 63, w = t >> 6;
    int l16 = lane & 15, quad = lane >> 4;
    int nt0 = (w < 3) ? w * 3 : 9 + (w - 3) * 2;

    if (bid < FILL_BLOCKS) {
        // ---------------- CSR fill (row, norm) ----------------
        int e = bid * 512 + t;
        if (e < N_EDGES) {
            int c = col[e], r = row[e];
            int p = atomicAdd(&cursor[c], 1);
            edge_pack[p] = make_int2(r, __float_as_int(dinv[r] * dinv[c]));
        }
    } else if (bid < FILL_BLOCKS + GEMMA_BLOCKS) {
        // ---------------- Part A layer-0 GEMM (exact 125 x 80 rows) --------
        int base = (bid - FILL_BLOCKS) * RBM;
        for (int i = t; i < RBM * 8; i += 512) {
            int r = i >> 3, c4 = (i & 7) * 4;
            const float* ar = edge_attr + (size_t)(base + r) * 3;
            float a0 = ar[0], a1 = ar[1], a2 = ar[2];
            s16x4 pk;
#pragma unroll
            for (int j = 0; j < 4; ++j) {
                int cc = c4 + j;
                float v = edge_b[cc];
                v = fmaf(a0, edge_w[cc], v);
                v = fmaf(a1, edge_w[32 + cc], v);
                v = fmaf(a2, edge_w[64 + cc], v);
                pk[j] = bf16r(v);
            }
            *(s16x4*)&Hh[r * KS + c4] = pk;
        }
        for (int i = t; i < RBM * 6; i += 512) {
            int r = i / 6, k = 304 + (i % 6) * 4;
            *(s16x4*)&Hh[r * KS + k] = (s16x4)0;
        }
        __syncthreads();
        if (w < 3) {
            f32x4 acc[5][3];
            kloop<5, 3, false>(wt0, 1, Hh, nt0, quad, l16, acc);
            gemm_out<5, 3>(base, nt0, quad, l16, acc, hw0);
        } else {
            f32x4 acc[5][2];
            kloop<5, 2, false>(wt0, 1, Hh, nt0, quad, l16, acc);
            gemm_out<5, 2>(base, nt0, quad, l16, acc, hw0);
        }
    } else {
        // ---------------- Part B unit (fused 5-layer), exact 80 rows -------
        int base = N_NODES + (bid - FILL_BLOCKS - GEMMA_BLOCKS) * RBM;
        for (int i = t; i < RBM * 8; i += 512) {
            int r = i >> 3, c4 = (i & 7) * 4;
            const float* ar = edge_attr + (size_t)(base + r) * 3;
            float a0 = ar[0], a1 = ar[1], a2 = ar[2];
            s16x4 pk;
#pragma unroll
            for (int j = 0; j < 4; ++j) {
                int cc = c4 + j;
                float v = edge_b[cc];
                v = fmaf(a0, edge_w[cc], v);
                v = fmaf(a1, edge_w[32 + cc], v);
                v = fmaf(a2, edge_w[64 + cc], v);
                pk[j] = bf16r(v);
            }
            *(s16x4*)&Hh[r * KS + c4] = pk;
        }
        for (int i = t; i < RBM * 6; i += 512) {
            int r = i / 6, k = 304 + (i % 6) * 4;
            *(s16x4*)&Hh[r * KS + k] = (s16x4)0;
        }
        __syncthreads();

        float* gout = gpartB + (size_t)(bid - FILL_BLOCKS - GEMMA_BLOCKS) * HIDP;
        if (w < 3) {
            f32x4 acc[5][3];
            kloop<5, 3, true>(wt0, 1, Hh, nt0, quad, l16, acc);
            __syncthreads();
            gcn_epilogueT<5, 3>(gcn0_b, nt0, quad, l16, acc, Hh);
            __syncthreads();
            for (int l = 0; l < 4; ++l) {
                kloop<5, 3, true>(wtl + (size_t)l * 194560, 10, Hh, nt0, quad, l16, acc);
                if (l < 3) {
                    __syncthreads();
                    gcn_epilogueT<5, 3>(gcn_b + l * HID, nt0, quad, l16, acc, Hh);
                    __syncthreads();
                } else {
                    gcn_finalT<5, 3>(gcn_b + l * HID, nt0, quad, l16, acc, gout);
                }
            }
        } else {
            f32x4 acc[5][2];
            kloop<5, 2, true>(wt0, 1, Hh, nt0, quad, l16, acc);
            __syncthreads();
            gcn_epilogueT<5, 2>(gcn0_b, nt0, quad, l16, acc, Hh);
            __syncthreads();
            for (int l = 0; l < 4; ++l) {
                kloop<5, 2, true>(wtl + (size_t)l * 194560, 10, Hh, nt0, quad, l16, acc);
                if (l < 3) {
                    __syncthreads();
                    gcn_epilogueT<5, 2>(gcn_b + l * HID, nt0, quad, l16, acc, Hh);
                    __syncthreads();
                } else {
                    gcn_finalT<5, 2>(gcn_b + l * HID, nt0, quad, l16, acc, gout);
                }
            }
        }
    }
}

// ---------------------------------------------------------------------------
// agg of one node's neighbor sum into v[5]: 8-deep unroll (40 gathers in
// flight) + 4 + scalar tail, for latency hiding at low block counts.
// ---------------------------------------------------------------------------
__device__ __forceinline__ void agg_row(int c, int lane,
                                        const unsigned short* __restrict__ hw_in,
                                        const int* __restrict__ col_start,
                                        const int2* __restrict__ edge_pack,
                                        float (&v)[5]) {
#pragma unroll
    for (int jj = 0; jj < 5; ++jj) v[jj] = 0.0f;
    int beg = col_start[c], end = col_start[c + 1];
    int i = beg;
#pragma unroll 1
    for (; i + 8 <= end; i += 8) {
        int2 e0 = edge_pack[i], e1 = edge_pack[i + 1];
        int2 e2 = edge_pack[i + 2], e3 = edge_pack[i + 3];
        int2 e4 = edge_pack[i + 4], e5 = edge_pack[i + 5];
        int2 e6 = edge_pack[i + 6], e7 = edge_pack[i + 7];
        const unsigned short* h0 = hw_in + (size_t)e0.x * HIDP;
        const unsigned short* h1 = hw_in + (size_t)e1.x * HIDP;
        const unsigned short* h2 = hw_in + (size_t)e2.x * HIDP;
        const unsigned short* h3 = hw_in + (size_t)e3.x * HIDP;
        const unsigned short* h4 = hw_in + (size_t)e4.x * HIDP;
        const unsigned short* h5 = hw_in + (size_t)e5.x * HIDP;
        const unsigned short* h6 = hw_in + (size_t)e6.x * HIDP;
        const unsigned short* h7 = hw_in + (size_t)e7.x * HIDP;
        float n0 = __int_as_float(e0.y), n1 = __int_as_float(e1.y);
        float n2 = __int_as_float(e2.y), n3 = __int_as_float(e3.y);
        float n4 = __int_as_float(e4.y), n5 = __int_as_float(e5.y);
        float n6 = __int_as_float(e6.y), n7 = __int_as_float(e7.y);
#pragma unroll
        for (int jj = 0; jj < 5; ++jj) {
            int cc = lane + 64 * jj;
            if (cc < HIDP) {
                float s = v[jj];
                s = fmaf(n0, b2f(h0[cc]), s);
                s = fmaf(n1, b2f(h1[cc]), s);
                s = fmaf(n2, b2f(h2[cc]), s);
                s = fmaf(n3, b2f(h3[cc]), s);
                s = fmaf(n4, b2f(h4[cc]), s);
                s = fmaf(n5, b2f(h5[cc]), s);
                s = fmaf(n6, b2f(h6[cc]), s);
                s = fmaf(n7, b2f(h7[cc]), s);
                v[jj] = s;
            }
        }
    }
#pragma unroll 1
    for (; i + 4 <= end; i += 4) {
        int2 e0 = edge_pack[i], e1 = edge_pack[i + 1];
        int2 e2 = edge_pack[i + 2], e3 = edge_pack[i + 3];
        const unsigned short* h0 = hw_in + (size_t)e0.x * HIDP;
        const unsigned short* h1 = hw_in + (size_t)e1.x * HIDP;
        const unsigned short* h2 = hw_in + (size_t)e2.x * HIDP;
        const unsigned short* h3 = hw_in + (size_t)e3.x * HIDP;
        float n0 = __int_as_float(e0.y), n1 = __int_as_float(e1.y);
        float n2 = __int_as_float(e2.y), n3 = __int_as_float(e3.y);
#pragma unroll
        for (int jj = 0; jj < 5; ++jj) {
            int cc = lane + 64 * jj;
            if (cc < HIDP) {
                float s = v[jj];
                s = fmaf(n0, b2f(h0[cc]), s);
                s = fmaf(n1, b2f(h1[cc]), s);
                s = fmaf(n2, b2f(h2[cc]), s);
                s = fmaf(n3, b2f(h3[cc]), s);
                v[jj] = s;
            }
        }
    }
#pragma unroll 1
    for (; i < end; ++i) {
        int2 e0 = edge_pack[i];
        const unsigned short* h0 = hw_in + (size_t)e0.x * HIDP;
        float n0 = __int_as_float(e0.y);
#pragma unroll
        for (int jj = 0; jj < 5; ++jj) {
            int cc = lane + 64 * jj;
            if (cc < HIDP) v[jj] = fmaf(n0, b2f(h0[cc]), v[jj]);
        }
    }
}

// ---------------------------------------------------------------------------
// k_fuse: agg(prev hw) -> relu+bias -> LDS -> gemm -> next hw.
// RBF=16 -> 625 blocks (grid utilization 61%->81% at 2 blocks/CU), each wave
// aggs 2 rows; GEMM is MT=1.
// ---------------------------------------------------------------------------
__global__ __launch_bounds__(512, 4) void k_fuse(
    const unsigned short* __restrict__ hw_in,
    const int* __restrict__ col_start,
    const int2* __restrict__ edge_pack,
    const float* __restrict__ selfnorm,
    const float* __restrict__ bias,
    const short* __restrict__ wt,
    unsigned short* __restrict__ hw_out) {
    __shared__ short Hh[RBF * KS];   // 10496 B
    int t = threadIdx.x;
    int lane = t & 63, w = t >> 6;
    int l16 = lane & 15, quad = lane >> 4;
    int base = blockIdx.x * RBF;
    int nt0 = (w < 3) ? w * 3 : 9 + (w - 3) * 2;

#pragma unroll 1
    for (int j = 0; j < 2; ++j) {
        int r = w * 2 + j;
        int c = base + r;                 // 625*16 == 10000: always valid
        float v[5];
        agg_row(c, lane, hw_in, col_start, edge_pack, v);
        float sn = selfnorm[c];
        const unsigned short* sp = hw_in + (size_t)c * HIDP;
#pragma unroll
        for (int jj = 0; jj < 5; ++jj) {
            int cc = lane + 64 * jj;
            if (cc < HIDP) {
                float h = v[jj] + sn * b2f(sp[cc]) + ((cc < HID) ? bias[cc] : 0.0f);
                Hh[r * KS + cc] = bf16r(fmaxf(h, 0.0f));
            }
        }
    }
    for (int i = t; i < RBF * 6; i += 512) {
        int r = i / 6, k = 304 + (i % 6) * 4;
        *(s16x4*)&Hh[r * KS + k] = (s16x4)0;
    }
    __syncthreads();

    if (w < 3) {
        f32x4 acc[1][3];
        kloop<1, 3, false>(wt, 10, Hh, nt0, quad, l16, acc);
        gemm_out<1, 3>(base, nt0, quad, l16, acc, hw_out);
    } else {
        f32x4 acc[1][2];
        kloop<1, 2, false>(wt, 10, Hh, nt0, quad, l16, acc);
        gemm_out<1, 2>(base, nt0, quad, l16, acc, hw_out);
    }
}

// ---------------------------------------------------------------------------
// k_last: final Part-A agg + colsum into g_sum, with gpartB fold absorbed
// (waves 0..2 each add one gpartB row; 625*3 == 1875 exact).
// ---------------------------------------------------------------------------
__global__ __launch_bounds__(512) void k_last(
    const unsigned short* __restrict__ hw_in,
    const int* __restrict__ col_start,
    const int2* __restrict__ edge_pack,
    const float* __restrict__ selfnorm,
    const float* __restrict__ bias,
    const float* __restrict__ gpartB,
    float* __restrict__ g_sum) {
    __shared__ float red[8 * 320];
    int t = threadIdx.x;
    int lane = t & 63, w = t >> 6;
    int base = blockIdx.x * RBF;

    float s[5] = {0.0f, 0.0f, 0.0f, 0.0f, 0.0f};
#pragma unroll 1
    for (int j = 0; j < 2; ++j) {
        int c = base + w * 2 + j;          // always valid
        float v[5];
        agg_row(c, lane, hw_in, col_start, edge_pack, v);
        float sn = selfnorm[c];
        const unsigned short* sp = hw_in + (size_t)c * HIDP;
#pragma unroll
        for (int jj = 0; jj < 5; ++jj) {
            int cc = lane + 64 * jj;
            if (cc < HID) {
                float h = v[jj] + sn * b2f(sp[cc]) + bias[cc];
                s[jj] += fmaxf(h, 0.0f);
            }
        }
    }
    // fold partB per-block partials (3 rows per block; 625*3 == 1875 exact)
    if (w < 3) {
        int rr = blockIdx.x * 3 + w;
        if (rr < PARTB_BLOCKS) {
#pragma unroll
            for (int jj = 0; jj < 5; ++jj) {
                int cc = lane + 64 * jj;
                if (cc < HID) s[jj] += gpartB[(size_t)rr * HIDP + cc];
            }
        }
    }
#pragma unroll
    for (int jj = 0; jj < 5; ++jj) red[w * 320 + lane + 64 * jj] = s[jj];
    __syncthreads();
    if (w == 0) {
#pragma unroll
        for (int jj = 0; jj < 5; ++jj) {
            int cc = lane + 64 * jj;
            if (cc < HID) {
                float tot = 0.0f;
#pragma unroll
                for (int g = 0; g < 8; ++g) tot += red[g * 320 + cc];
                atomicAdd(&g_sum[cc], tot);
            }
        }
    }
}

__global__ void k_head(const float* __restrict__ g_sum,
                       const float* __restrict__ lin1_w, const float* __restrict__ lin1_b,
                       const float* __restrict__ lin2_w, const float* __restrict__ lin2_b,
                       float* __restrict__ out) {
    __shared__ float g2[32];
    int t = threadIdx.x;
    const float inv = 1.0f / (float)N_EDGES;
    if (t < 32) {
        float a = lin1_b[t];
        for (int d = 0; d < HID; ++d) a = fmaf(g_sum[d] * inv, lin1_w[d * 32 + t], a);
        g2[t] = fmaxf(a, 0.0f);
    }
    __syncthreads();
    if (t < 2) {
        float p = lin2_b[t];
        for (int j = 0; j < 32; ++j) p = fmaf(g2[j], lin2_w[j * 2 + t], p);
        out[t] = p;
    }
}

// ---------------------------------------------------------------------------

extern "C" void kernel_launch(void* const* d_in, const int* in_sizes, int n_in,
                              void* d_out, int out_size, void* d_ws, size_t ws_size,
                              hipStream_t stream) {
    (void)in_sizes; (void)n_in; (void)out_size; (void)ws_size;
    const int* edge_index = (const int*)d_in[1];
    const float* edge_attr = (const float*)d_in[2];
    const float* edge_w = (const float*)d_in[6];
    const float* edge_b = (const float*)d_in[7];
    const float* gcn0_w = (const float*)d_in[8];
    const float* gcn0_b = (const float*)d_in[9];
    const float* gcn_w = (const float*)d_in[10];
    const float* gcn_b = (const float*)d_in[11];
    const float* lin1_w = (const float*)d_in[12];
    const float* lin1_b = (const float*)d_in[13];
    const float* lin2_w = (const float*)d_in[14];
    const float* lin2_b = (const float*)d_in[15];

    char* ws = (char*)d_ws;
    size_t off = 0;
    auto alloc = [&](size_t bytes) {
        void* p = ws + off;
        off = (off + bytes + 255) & ~(size_t)255;
        return p;
    };
    unsigned short* hwA = (unsigned short*)alloc((size_t)N_NODES * HIDP * 2);
    unsigned short* hwB = (unsigned short*)alloc((size_t)N_NODES * HIDP * 2);
    int2* edge_pack = (int2*)alloc((size_t)N_EDGES * 8);
    int* cnt = (int*)alloc((size_t)N_NODES * 4);
    int* col_start = (int*)alloc((size_t)(N_NODES + 1) * 4);
    int* cursor = (int*)alloc((size_t)N_NODES * 4);
    float* dinv = (float*)alloc((size_t)N_NODES * 4);
    float* selfnorm = (float*)alloc((size_t)N_NODES * 4);
    float* g_sum = (float*)alloc((size_t)HIDP * 4);
    short* wt0 = (short*)alloc((size_t)38912);
    short* wtl = (short*)alloc((size_t)4 * 389120);
    float* gpartB = (float*)alloc((size_t)PARTB_BLOCKS * HIDP * 4);

    const int* row = edge_index;
    const int* col = edge_index + N_EDGES;

    hipMemsetAsync(cnt, 0, N_NODES * 4, stream);
    hipMemsetAsync(g_sum, 0, HIDP * 4, stream);

    k_prep<<<(N_EDGES + 255) / 256, 256, 0, stream>>>(gcn0_w, gcn_w, wt0, wtl, col, cnt);
    k_scan<<<1, 1024, 0, stream>>>(cnt, col_start, cursor, dinv, selfnorm);

    // mega: CSR fill (first) + Part-A L0 + partB (80-row blocks, heavy tail)
    k_mega<<<MEGA_BLOCKS, 512, 0, stream>>>(edge_attr, edge_w, edge_b, wt0, wtl,
                                            gcn0_b, gcn_b, gpartB, hwA,
                                            row, col, cursor, dinv, edge_pack);

    // Part A layers 1..4: fused agg+gemm per layer (625 blocks each)
    k_fuse<<<FUSE_BLOCKS, 512, 0, stream>>>(hwA, col_start, edge_pack, selfnorm,
                                            gcn0_b, wtl + (size_t)0 * 194560, hwB);
    k_fuse<<<FUSE_BLOCKS, 512, 0, stream>>>(hwB, col_start, edge_pack, selfnorm,
                                            gcn_b + 0 * HID, wtl + (size_t)1 * 194560, hwA);
    k_fuse<<<FUSE_BLOCKS, 512, 0, stream>>>(hwA, col_start, edge_pack, selfnorm,
                                            gcn_b + 1 * HID, wtl + (size_t)2 * 194560, hwB);
    k_fuse<<<FUSE_BLOCKS, 512, 0, stream>>>(hwB, col_start, edge_pack, selfnorm,
                                            gcn_b + 2 * HID, wtl + (size_t)3 * 194560, hwA);
    // final agg + colsum + partB fold, then head
    k_last<<<FUSE_BLOCKS, 512, 0, stream>>>(hwA, col_start, edge_pack, selfnorm,
                                            gcn_b + 3 * HID, gpartB, g_sum);
    k_head<<<1, 64, 0, stream>>>(g_sum, lin1_w, lin1_b, lin2_w, lin2_b, (float*)d_out);
}